// Round 16
// baseline (187.065 us; speedup 1.0000x reference)
//
#include <hip/hip_runtime.h>
#include <hip/hip_bf16.h>

typedef __attribute__((ext_vector_type(8))) short bf16x8;
typedef __attribute__((ext_vector_type(4))) float f32x4;

#define KDIM 2048
#define BK 64
#define NT (KDIM / BK)

__device__ __forceinline__ unsigned short f2bf(float f) {
  union { float fv; unsigned int u; } c; c.fv = f;
  unsigned int u = c.u;
  unsigned int r = (u + 0x7FFFu + ((u >> 16) & 1u)) >> 16;
  return (unsigned short)r;
}

__device__ __forceinline__ void gload_lds16(const unsigned short* g, unsigned short* l) {
  auto gp = reinterpret_cast<const __attribute__((address_space(1))) unsigned int*>(
      reinterpret_cast<uintptr_t>(g));
  auto lp = reinterpret_cast<__attribute__((address_space(3))) unsigned int*>(
      reinterpret_cast<uintptr_t>(l));
  __builtin_amdgcn_global_load_lds(gp, lp, 16, 0, 0);
}

__device__ __forceinline__ float sigm(float z) { return 1.0f / (1.0f + __expf(-z)); }
__device__ __forceinline__ float tanh_fast(float z) { return 1.0f - 2.0f / (__expf(2.0f * z) + 1.0f); }

__global__ void pack_hx_kernel(const float* __restrict__ x, const float* __restrict__ h,
                               unsigned short* __restrict__ hx) {
  int idx = (blockIdx.x * blockDim.x + threadIdx.x) * 4;
  int row = idx >> 11;
  int col = idx & 2047;
  const float* src = (col < 1024) ? (x + (size_t)row * 1024 + col)
                                  : (h + (size_t)row * 1024 + (col - 1024));
  float4 v = *reinterpret_cast<const float4*>(src);
  ushort4 o = make_ushort4(f2bf(v.x), f2bf(v.y), f2bf(v.z), f2bf(v.w));
  *reinterpret_cast<ushort4*>(hx + idx) = o;
}

__global__ void transpose_w4_kernel(const float* __restrict__ W0, const float* __restrict__ W1,
                                    const float* __restrict__ W2, const float* __restrict__ W3,
                                    unsigned short* __restrict__ Wt) {
  __shared__ float tile[32][33];
  const int g = blockIdx.z;
  const float* W = (g == 0) ? W0 : (g == 1) ? W1 : (g == 2) ? W2 : W3;
  unsigned short* T = Wt + (size_t)g * 1024 * 2048;
  int n0 = blockIdx.x * 32;
  int k0 = blockIdx.y * 32;
  int tx = threadIdx.x;
  int ty = threadIdx.y;
#pragma unroll
  for (int i = 0; i < 4; ++i)
    tile[ty + 8 * i][tx] = W[(size_t)(k0 + ty + 8 * i) * 1024 + (n0 + tx)];
  __syncthreads();
#pragma unroll
  for (int i = 0; i < 4; ++i)
    T[(size_t)(n0 + ty + 8 * i) * 2048 + (k0 + tx)] = f2bf(tile[tx][ty + 8 * i]);
}

#define BAR  asm volatile("s_barrier" ::: "memory")
#define LGKM0 asm volatile("s_waitcnt lgkmcnt(0)" ::: "memory")
#define VMC(N) asm volatile("s_waitcnt vmcnt(" #N ")" ::: "memory")

#define READ_AF()                                                               \
  {                                                                             \
    _Pragma("unroll") for (int m = 0; m < 4; ++m)                               \
        _Pragma("unroll") for (int ks = 0; ks < 2; ++ks)                        \
            aF[m][ks] = *reinterpret_cast<const bf16x8*>(Ab + aoff[m][ks]);     \
  }

#define READ_BF(G)                                                              \
  {                                                                             \
    _Pragma("unroll") for (int n = 0; n < 2; ++n)                               \
        _Pragma("unroll") for (int ks = 0; ks < 2; ++ks)                        \
            bF[n][ks] = *reinterpret_cast<const bf16x8*>(Bb + (G)*4096 + boff[n][ks]); \
  }

#define MFMA_GATE(G)                                                            \
  __builtin_amdgcn_s_setprio(1);                                                \
  _Pragma("unroll") for (int m = 0; m < 4; ++m)                                 \
      _Pragma("unroll") for (int n = 0; n < 2; ++n)                             \
          _Pragma("unroll") for (int ks = 0; ks < 2; ++ks)                      \
              acc[G][m][n] = __builtin_amdgcn_mfma_f32_16x16x32_bf16(           \
                  aF[m][ks], bF[n][ks], acc[G][m][n], 0, 0, 0);                 \
  __builtin_amdgcn_s_setprio(0);

// ================= real kernel: R8 verbatim =================
__global__ __launch_bounds__(512, 2) void lstm_fused_kernel(
    const unsigned short* __restrict__ hx,
    const unsigned short* __restrict__ wtb,
    const float* __restrict__ bias_f,
    const float* __restrict__ bias_i,
    const float* __restrict__ bias_s,
    const float* __restrict__ bias_p,
    const float* __restrict__ c_in,
    float* __restrict__ out) {
  __shared__ unsigned short lA[2][256 * BK];
  __shared__ unsigned short lB[2][4 * 64 * BK];

  const int tid  = threadIdx.x;
  const int lane = tid & 63;
  const int wid  = tid >> 6;
  const int wr   = wid >> 1;
  const int wc   = wid & 1;
  const int lg   = lane >> 4;
  const int ll   = lane & 15;

  const int wg   = (blockIdx.x & 7) * 32 + (blockIdx.x >> 3);
  const int brow = wg >> 4;
  const int bcol = wg & 15;

  const unsigned short* srcA[4];
  unsigned int dA[4];
#pragma unroll
  for (int i = 0; i < 4; ++i) {
    int s = i * 512 + tid;
    int r = s >> 3, sch = s & 7;
    int ch = sch ^ (r & 7);
    srcA[i] = hx + (size_t)(brow * 256 + r) * KDIM + ch * 8;
    dA[i] = s * 8;
  }
  const unsigned short* srcB[4];
  unsigned int dB[4];
  {
    int r = tid >> 3, sch = tid & 7;
    int ch = sch ^ (r & 7);
#pragma unroll
    for (int g = 0; g < 4; ++g) {
      srcB[g] = wtb + (size_t)g * 1024 * 2048 + (size_t)(bcol * 64 + r) * KDIM + ch * 8;
      dB[g] = g * 4096 + tid * 8;
    }
  }

  unsigned int aoff[4][2], boff[2][2];
#pragma unroll
  for (int m = 0; m < 4; ++m) {
    int row = wr * 64 + m * 16 + ll;
#pragma unroll
    for (int ks = 0; ks < 2; ++ks) {
      int ch = (ks * 4 + lg) ^ (row & 7);
      aoff[m][ks] = row * 64 + ch * 8;
    }
  }
#pragma unroll
  for (int n = 0; n < 2; ++n) {
    int row = wc * 32 + n * 16 + ll;
#pragma unroll
    for (int ks = 0; ks < 2; ++ks) {
      int ch = (ks * 4 + lg) ^ (row & 7);
      boff[n][ks] = row * 64 + ch * 8;
    }
  }

  f32x4 acc[4][4][2];
#pragma unroll
  for (int g = 0; g < 4; ++g)
#pragma unroll
    for (int m = 0; m < 4; ++m)
#pragma unroll
      for (int n = 0; n < 2; ++n)
        acc[g][m][n] = (f32x4)(0.0f);

  gload_lds16(srcB[0], &lB[0][dB[0]]);
  gload_lds16(srcB[1], &lB[0][dB[1]]);
  gload_lds16(srcA[0], &lA[0][dA[0]]);
  gload_lds16(srcA[1], &lA[0][dA[1]]);
  gload_lds16(srcA[2], &lA[0][dA[2]]);
  gload_lds16(srcA[3], &lA[0][dA[3]]);
  gload_lds16(srcB[2], &lB[0][dB[2]]);
  gload_lds16(srcB[3], &lB[0][dB[3]]);
#pragma unroll
  for (int i = 0; i < 4; ++i) { srcA[i] += BK; srcB[i] += BK; }
  VMC(0);
  BAR;

  for (int t = 0; t < NT - 1; ++t) {
    const int P = t & 1;
    const unsigned short* Ab = &lA[P][0];
    const unsigned short* Bb = &lB[P][0];
    unsigned short* An = &lA[P ^ 1][0];
    unsigned short* Bn = &lB[P ^ 1][0];

    bf16x8 aF[4][2];
    bf16x8 bF[2][2];

    READ_AF()
    READ_BF(0)
    gload_lds16(srcB[0], Bn + dB[0]);
    gload_lds16(srcB[1], Bn + dB[1]);
    BAR;
    LGKM0;
    MFMA_GATE(0)
    BAR;

    READ_BF(1)
    gload_lds16(srcA[0], An + dA[0]);
    gload_lds16(srcA[1], An + dA[1]);
    BAR;
    LGKM0;
    MFMA_GATE(1)
    VMC(4);
    BAR;

    READ_BF(2)
    gload_lds16(srcA[2], An + dA[2]);
    gload_lds16(srcA[3], An + dA[3]);
    BAR;
    LGKM0;
    MFMA_GATE(2)
    BAR;

    READ_BF(3)
    gload_lds16(srcB[2], Bn + dB[2]);
    gload_lds16(srcB[3], Bn + dB[3]);
    BAR;
    LGKM0;
    MFMA_GATE(3)
    VMC(2);
    BAR;

#pragma unroll
    for (int i = 0; i < 4; ++i) { srcA[i] += BK; srcB[i] += BK; }
  }

  {
    const int P = (NT - 1) & 1;
    const unsigned short* Ab = &lA[P][0];
    const unsigned short* Bb = &lB[P][0];

    bf16x8 aF[4][2];
    bf16x8 bF[2][2];

    READ_AF()
    READ_BF(0)
    BAR;
    LGKM0;
    MFMA_GATE(0)
    BAR;

    READ_BF(1)
    BAR;
    LGKM0;
    MFMA_GATE(1)
    VMC(0);
    BAR;

    READ_BF(2)
    BAR;
    LGKM0;
    MFMA_GATE(2)
    BAR;

    READ_BF(3)
    BAR;
    LGKM0;
    MFMA_GATE(3)
  }

  const int row0 = brow * 256 + wr * 64;
  const int col0 = bcol * 64 + wc * 32;
  float bv[4][2];
#pragma unroll
  for (int n = 0; n < 2; ++n) {
    int col = col0 + n * 16 + ll;
    bv[0][n] = bias_f[col];
    bv[1][n] = bias_i[col];
    bv[2][n] = bias_s[col];
    bv[3][n] = bias_p[col];
  }
#pragma unroll
  for (int m = 0; m < 4; ++m)
#pragma unroll
    for (int n = 0; n < 2; ++n)
#pragma unroll
      for (int j = 0; j < 4; ++j) {
        int row = row0 + m * 16 + lg * 4 + j;
        int col = col0 + n * 16 + ll;
        float zf = acc[0][m][n][j] + bv[0][n];
        float zi = acc[1][m][n][j] + bv[1][n];
        float zs = acc[2][m][n][j] + bv[2][n];
        float zp = acc[3][m][n][j] + bv[3][n];
        float fg = sigm(zf);
        float ig = sigm(zi);
        float sg = sigm(zs);
        float pg = tanh_fast(zp);
        float cn = c_in[(size_t)row * 1024 + col] * fg + ig * pg;
        out[(size_t)row * 1024 + col] = tanh_fast(cn) * sg;
      }
}

// ================= probe A: MFMA only (calibration) =================
__global__ __launch_bounds__(512, 2) void probe_mfma_only(float* __restrict__ scr) {
  __shared__ unsigned short lA[2][256 * BK];
  __shared__ unsigned short lB[2][4 * 64 * BK];
  const int tid = threadIdx.x;
  lA[0][tid] = (unsigned short)tid;
  lB[0][tid] = (unsigned short)tid;

  f32x4 acc[4][4][2];
#pragma unroll
  for (int g = 0; g < 4; ++g)
#pragma unroll
    for (int m = 0; m < 4; ++m)
#pragma unroll
      for (int n = 0; n < 2; ++n)
        acc[g][m][n] = (f32x4)(0.0f);

  bf16x8 one;
#pragma unroll
  for (int j = 0; j < 8; ++j) one[j] = (short)0x3F80;
  bf16x8 aF[4][2], bF[2][2];
#pragma unroll
  for (int m = 0; m < 4; ++m) { aF[m][0] = one; aF[m][1] = one; }
#pragma unroll
  for (int n = 0; n < 2; ++n) { bF[n][0] = one; bF[n][1] = one; }

  for (int t = 0; t < NT; ++t) {
    MFMA_GATE(0)
    MFMA_GATE(1)
    MFMA_GATE(2)
    MFMA_GATE(3)
  }

  float s = 0.0f;
#pragma unroll
  for (int g = 0; g < 4; ++g)
#pragma unroll
    for (int m = 0; m < 4; ++m)
#pragma unroll
      for (int n = 0; n < 2; ++n)
        s += acc[g][m][n][0];
  s += (float)lA[0][(tid + 1) & 511] + (float)lB[0][(tid + 1) & 511];
  scr[blockIdx.x * 512 + tid] = s;
}

// ================= probe B: ds_read + MFMA (no staging, no barriers in loop) =================
__global__ __launch_bounds__(512, 2) void probe_ds_mfma(
    const unsigned short* __restrict__ hx,
    const unsigned short* __restrict__ wtb,
    float* __restrict__ scr) {
  __shared__ unsigned short lA[2][256 * BK];
  __shared__ unsigned short lB[2][4 * 64 * BK];

  const int tid  = threadIdx.x;
  const int lane = tid & 63;
  const int wid  = tid >> 6;
  const int wr   = wid >> 1;
  const int wc   = wid & 1;
  const int lg   = lane >> 4;
  const int ll   = lane & 15;

  // fill both buffers once (content irrelevant but defined)
  {
    int r = tid >> 3, sch = tid & 7;
    int ch = sch ^ (r & 7);
    const unsigned short* sa = hx + (size_t)r * KDIM + ch * 8;
    const unsigned short* sb = wtb + (size_t)r * KDIM + ch * 8;
#pragma unroll
    for (int i = 0; i < 4; ++i) {
      gload_lds16(sa + (size_t)i * 64 * KDIM, &lA[0][i * 4096 + tid * 8]);
      gload_lds16(sb + (size_t)i * 64 * KDIM, &lB[0][i * 4096 + tid * 8]);
      gload_lds16(sa + (size_t)i * 64 * KDIM + BK, &lA[1][i * 4096 + tid * 8]);
      gload_lds16(sb + (size_t)i * 64 * KDIM + BK, &lB[1][i * 4096 + tid * 8]);
    }
  }
  VMC(0);
  BAR;

  unsigned int aoff[4][2], boff[2][2];
#pragma unroll
  for (int m = 0; m < 4; ++m) {
    int row = wr * 64 + m * 16 + ll;
#pragma unroll
    for (int ks = 0; ks < 2; ++ks) {
      int ch = (ks * 4 + lg) ^ (row & 7);
      aoff[m][ks] = row * 64 + ch * 8;
    }
  }
#pragma unroll
  for (int n = 0; n < 2; ++n) {
    int row = wc * 32 + n * 16 + ll;
#pragma unroll
    for (int ks = 0; ks < 2; ++ks) {
      int ch = (ks * 4 + lg) ^ (row & 7);
      boff[n][ks] = row * 64 + ch * 8;
    }
  }

  f32x4 acc[4][4][2];
#pragma unroll
  for (int g = 0; g < 4; ++g)
#pragma unroll
    for (int m = 0; m < 4; ++m)
#pragma unroll
      for (int n = 0; n < 2; ++n)
        acc[g][m][n] = (f32x4)(0.0f);

  for (int t = 0; t < NT; ++t) {
    const int P = t & 1;
    const unsigned short* Ab = &lA[P][0];
    const unsigned short* Bb = &lB[P][0];

    bf16x8 aF[4][2];
    bf16x8 bF[2][2];

    READ_AF()
    READ_BF(0)
    LGKM0;
    MFMA_GATE(0)
    READ_BF(1)
    LGKM0;
    MFMA_GATE(1)
    READ_BF(2)
    LGKM0;
    MFMA_GATE(2)
    READ_BF(3)
    LGKM0;
    MFMA_GATE(3)
  }

  float s = 0.0f;
#pragma unroll
  for (int g = 0; g < 4; ++g)
#pragma unroll
    for (int m = 0; m < 4; ++m)
#pragma unroll
      for (int n = 0; n < 2; ++n)
        s += acc[g][m][n][0];
  scr[blockIdx.x * 512 + tid] = s;
}

// ================= probe C: gload_lds staging + MFMA (no ds_reads, no barriers) =================
__global__ __launch_bounds__(512, 2) void probe_stage_mfma(
    const unsigned short* __restrict__ hx,
    const unsigned short* __restrict__ wtb,
    float* __restrict__ scr) {
  __shared__ unsigned short lA[2][256 * BK];
  __shared__ unsigned short lB[2][4 * 64 * BK];

  const int tid = threadIdx.x;
  const int wg   = (blockIdx.x & 7) * 32 + (blockIdx.x >> 3);
  const int brow = wg >> 4;
  const int bcol = wg & 15;

  const unsigned short* srcA[4];
  unsigned int dA[4];
#pragma unroll
  for (int i = 0; i < 4; ++i) {
    int s = i * 512 + tid;
    int r = s >> 3, sch = s & 7;
    int ch = sch ^ (r & 7);
    srcA[i] = hx + (size_t)(brow * 256 + r) * KDIM + ch * 8;
    dA[i] = s * 8;
  }
  const unsigned short* srcB[4];
  unsigned int dB[4];
  {
    int r = tid >> 3, sch = tid & 7;
    int ch = sch ^ (r & 7);
#pragma unroll
    for (int g = 0; g < 4; ++g) {
      srcB[g] = wtb + (size_t)g * 1024 * 2048 + (size_t)(bcol * 64 + r) * KDIM + ch * 8;
      dB[g] = g * 4096 + tid * 8;
    }
  }

#define PSTAGE(P)                                                       \
  {                                                                     \
    _Pragma("unroll") for (int i = 0; i < 4; ++i)                       \
        gload_lds16(srcA[i], &lA[P][dA[i]]);                            \
    _Pragma("unroll") for (int g = 0; g < 4; ++g)                       \
        gload_lds16(srcB[g], &lB[P][dB[g]]);                            \
    _Pragma("unroll") for (int i = 0; i < 4; ++i) srcA[i] += BK;        \
    _Pragma("unroll") for (int g = 0; g < 4; ++g) srcB[g] += BK;        \
  }

  f32x4 acc[4][4][2];
#pragma unroll
  for (int g = 0; g < 4; ++g)
#pragma unroll
    for (int m = 0; m < 4; ++m)
#pragma unroll
      for (int n = 0; n < 2; ++n)
        acc[g][m][n] = (f32x4)(0.0f);

  bf16x8 one;
#pragma unroll
  for (int j = 0; j < 8; ++j) one[j] = (short)0x3F80;
  bf16x8 aF[4][2], bF[2][2];
#pragma unroll
  for (int m = 0; m < 4; ++m) { aF[m][0] = one; aF[m][1] = one; }
#pragma unroll
  for (int n = 0; n < 2; ++n) { bF[n][0] = one; bF[n][1] = one; }

  PSTAGE(0)
  PSTAGE(1)

  for (int t = 0; t < NT; ++t) {
    VMC(8);  // retire tile t's 8 loads; keep next tile's 8 in flight
    MFMA_GATE(0)
    MFMA_GATE(1)
    MFMA_GATE(2)
    MFMA_GATE(3)
    if (t < NT - 2) PSTAGE(t & 1)
  }
  VMC(0);

  float s = 0.0f;
#pragma unroll
  for (int g = 0; g < 4; ++g)
#pragma unroll
    for (int m = 0; m < 4; ++m)
#pragma unroll
      for (int n = 0; n < 2; ++n)
        s += acc[g][m][n][0];
  s += (float)lA[0][tid] + (float)lB[0][tid];
  scr[blockIdx.x * 512 + tid] = s;
}

extern "C" void kernel_launch(void* const* d_in, const int* in_sizes, int n_in,
                              void* d_out, int out_size, void* d_ws, size_t ws_size,
                              hipStream_t stream) {
  const float* x  = (const float*)d_in[0];
  const float* h  = (const float*)d_in[1];
  const float* c  = (const float*)d_in[2];
  const float* Wf = (const float*)d_in[3];
  const float* bf = (const float*)d_in[4];
  const float* Wi = (const float*)d_in[5];
  const float* bi = (const float*)d_in[6];
  const float* Ws = (const float*)d_in[7];
  const float* bs = (const float*)d_in[8];
  const float* Wp = (const float*)d_in[9];
  const float* bp = (const float*)d_in[10];
  float* out = (float*)d_out;

  unsigned short* ws = (unsigned short*)d_ws;
  unsigned short* hx  = ws;
  unsigned short* wtb = ws + (size_t)4096 * 2048;
  float* scr = (float*)d_ws;  // probe sink (aliases hx; hx rebuilt each replay)

  pack_hx_kernel<<<(4096 * 2048 / 4) / 256, 256, 0, stream>>>(x, h, hx);

  dim3 tb(32, 8);
  dim3 tg(1024 / 32, 2048 / 32, 4);
  transpose_w4_kernel<<<tg, tb, 0, stream>>>(Wf, Wi, Ws, Wp, wtb);

  lstm_fused_kernel<<<256, 512, 0, stream>>>(hx, wtb, bf, bi, bs, bp, c, out);

  probe_mfma_only<<<256, 512, 0, stream>>>(scr);
  probe_ds_mfma<<<256, 512, 0, stream>>>(hx, wtb, scr);
  probe_stage_mfma<<<256, 512, 0, stream>>>(hx, wtb, scr);
}